// Round 10
// baseline (127.280 us; speedup 1.0000x reference)
//
#include <hip/hip_runtime.h>

// hashNeRF fused forward, MFMA edition, v7: zero-LDS permuted pipeline x 2-tile ILP.
//
// Verified: hash == parity(ix)^parity(iy), only HT[0:2,0:4,0:2] read; fragment
// layouts A row=lane&15 k=8*(lane>>4)+e / B col=lane&15 / D col=lane&15
// row=4*(lane>>4)+reg; pure bf16 absmax 0.0 (r8); neuron-permutation
// pi(16t+4g+r)=32(t&1)+4(t>>1)+8g+r makes D-quads == next layer's B-frags
// with identity k (r9, absmax 0.0).
// r8/r9 lesson: kernel is ~85% VALU by issue (encode+handoff ~600cyc/tile vs
// 110cyc MFMA); at ~1-2 waves/SIMD the serial chain exposes all latency
// (42us vs ~9us issue floor). r7's 2-tile "null" was measured in the
// 1-wave/SIMD split regime -> invalid there; registers now fit 2 waves/SIMD.
// Round-10: TWO tiles in flight per wave on the zero-LDS pipeline ->
// 4 independent chains per SIMD to fill VALU/MFMA/DS dep stalls.

typedef float  f32x4  __attribute__((ext_vector_type(4)));
typedef __bf16 bf16x8 __attribute__((ext_vector_type(8)));

#define MFMA16(A, B, C) __builtin_amdgcn_mfma_f32_16x16x32_bf16((A), (B), (C), 0, 0, 0)

__global__ __launch_bounds__(256) void hashnerf_mfma(
    const float* __restrict__ X,
    const float* __restrict__ HT,
    const float* __restrict__ W1, const float* __restrict__ B1,
    const float* __restrict__ W2, const float* __restrict__ B2,
    const float* __restrict__ W3, const float* __restrict__ B3,
    const float* __restrict__ W4, const float* __restrict__ B4,
    float* __restrict__ out, int npts)
{
    __shared__ __align__(16) float sBias[208];

    const int tid = threadIdx.x;
    if (tid < 64) {
        // stage biases PERMUTED: phys slot rho holds B[pi(rho)]
        const int pm = 32 * ((tid >> 4) & 1) + 4 * (tid >> 5)
                     + 8 * ((tid >> 2) & 3) + (tid & 3);
        sBias[tid]       = B1[pm];
        sBias[64 + tid]  = B2[pm];
        sBias[128 + tid] = B3[pm];
    }
    if (tid < 16) sBias[192 + tid] = (tid < 3) ? B4[tid] : 0.0f;
    __syncthreads();

    const int l = tid & 63;
    const int p = l & 15;      // point-in-tile (B/D col), A row
    const int g = l >> 4;      // lane group: K-chunk / D-row-quad selector

    // permuted output column for A fragments of W1/W2/W3: pi(16t + p)
    int po[4];
#pragma unroll
    for (int t = 0; t < 4; ++t)
        po[t] = 32 * (t & 1) + 4 * (t >> 1) + 8 * (p >> 2) + (p & 3);

    // ---- one-time per-wave: bf16 weight fragments (A = W^T) ----
    bf16x8 w1h[4];                       // L1: 32->64, out-permuted
#pragma unroll
    for (int t = 0; t < 4; ++t)
#pragma unroll
        for (int e = 0; e < 8; ++e)
            w1h[t][e] = (__bf16)W1[(8 * g + e) * 64 + po[t]];

    bf16x8 w2h[4][2], w3h[4][2];         // L2/L3: 64->64, k identity, out-permuted
#pragma unroll
    for (int t = 0; t < 4; ++t)
#pragma unroll
        for (int s = 0; s < 2; ++s)
#pragma unroll
            for (int e = 0; e < 8; ++e) {
                w2h[t][s][e] = (__bf16)W2[(32 * s + 8 * g + e) * 64 + po[t]];
                w3h[t][s][e] = (__bf16)W3[(32 * s + 8 * g + e) * 64 + po[t]];
            }

    bf16x8 w4h[2];                       // L4: 64->3, k identity, out identity
#pragma unroll
    for (int s = 0; s < 2; ++s)
#pragma unroll
        for (int e = 0; e < 8; ++e)
            w4h[s][e] = (p < 3) ? (__bf16)W4[(32 * s + 8 * g + e) * 3 + p] : (__bf16)0.0f;

    // hash-table constants (the only 16 floats ever used)
    float t0[8], t1[8];
#pragma unroll
    for (int e = 0; e < 8; ++e) { t0[e] = HT[e]; t1[e] = HT[524288 + e]; }

    // this lane's 4 resolution levels (levels 4g..4g+3)
    const float NVA[4] = {16.f, 17.f, 19.f, 21.f};
    const float NVB[4] = {23.f, 25.f, 27.f, 30.f};
    const float NVC[4] = {33.f, 36.f, 40.f, 44.f};
    const float NVD[4] = {48.f, 53.f, 58.f, 64.f};
    float nv4[4];
#pragma unroll
    for (int j = 0; j < 4; ++j)
        nv4[j] = (g == 0) ? NVA[j] : (g == 1) ? NVB[j] : (g == 2) ? NVC[j] : NVD[j];

    // encode: lane produces enc[8g..8g+7] of its point (bit-exact vs reference)
    auto encode = [&](float2 xv) -> bf16x8 {
        bf16x8 bh;
#pragma unroll
        for (int j2 = 0; j2 < 4; ++j2) {
            const float nv = nv4[j2];
            const float sx = xv.x * nv, sy = xv.y * nv;
            const float fx = sx - floorf(sx), fy = sy - floorf(sy);
            const unsigned ix = (unsigned)sx, iy = (unsigned)sy;
            const bool px = (ix & 1u) != 0u, py = (iy & 1u) != 0u;
            const bool pz = px != py;
            const float cx = 1.f - fx, cy = 1.f - fy;
            const float q0 = cx * cy, q1 = cx * fy, q2 = fx * cy, q3 = fx * fy;
            float a0 = q0 * t0[0];
            a0 = fmaf(q1, py ? t1[2] : t0[2], a0);
            a0 = fmaf(q2, px ? t1[4] : t0[4], a0);
            a0 = fmaf(q3, pz ? t1[6] : t0[6], a0);
            float a1 = q0 * t0[1];
            a1 = fmaf(q1, py ? t1[3] : t0[3], a1);
            a1 = fmaf(q2, px ? t1[5] : t0[5], a1);
            a1 = fmaf(q3, pz ? t1[7] : t0[7], a1);
            bh[2 * j2]     = (__bf16)a0;
            bh[2 * j2 + 1] = (__bf16)a1;
        }
        return bh;
    };

    // in-register handoff: lrelu + bf16, D quads -> next layer's B fragments
    auto handoff = [&](const f32x4 (&a)[4], bf16x8& x0, bf16x8& x1) {
#pragma unroll
        for (int r = 0; r < 4; ++r) {
            float v0 = fmaxf(a[0][r], 0.01f * a[0][r]);
            float v1 = fmaxf(a[1][r], 0.01f * a[1][r]);
            float v2 = fmaxf(a[2][r], 0.01f * a[2][r]);
            float v3 = fmaxf(a[3][r], 0.01f * a[3][r]);
            x0[r]     = (__bf16)v0;   // k = 8g+r
            x0[4 + r] = (__bf16)v2;   // k = 8g+4+r
            x1[r]     = (__bf16)v1;   // k = 32+8g+r
            x1[4 + r] = (__bf16)v3;   // k = 32+8g+4+r
        }
    };

    const int wave_global = blockIdx.x * 4 + (tid >> 6);
    const int nw = gridDim.x * 4;               // 2048 waves
    const int ntiles = (npts + 15) >> 4;        // 32768
    const float2* X2 = reinterpret_cast<const float2*>(X);

    int tA = wave_global;
    int tB = wave_global + nw;
    float2 xA = make_float2(0.f, 0.f), xB = xA;
    if (tA < ntiles) xA = X2[min(tA * 16 + p, npts - 1)];
    if (tB < ntiles) xB = X2[min(tB * 16 + p, npts - 1)];

    for (; tA < ntiles; tA += 2 * nw, tB += 2 * nw) {
        const int nA = tA + 2 * nw, nB = tB + 2 * nw;
        float2 xnA = xA, xnB = xB;
        if (nA < ntiles) xnA = X2[min(nA * 16 + p, npts - 1)];
        if (nB < ntiles) xnB = X2[min(nB * 16 + p, npts - 1)];
        const bool hasB = (tB < ntiles);

        // ---- encode both tiles (independent chains) ----
        bf16x8 bhA = encode(xA);
        bf16x8 bhB = encode(xB);

        // ---- L1: 32 -> 64 (out-permuted), both ----
        f32x4 aA[4], aB[4];
#pragma unroll
        for (int t = 0; t < 4; ++t) {
            aA[t] = *reinterpret_cast<const f32x4*>(&sBias[16 * t + 4 * g]);
            aB[t] = aA[t];
            aA[t] = MFMA16(w1h[t], bhA, aA[t]);
            aB[t] = MFMA16(w1h[t], bhB, aB[t]);
        }
        bf16x8 x0A, x1A, x0B, x1B;
        handoff(aA, x0A, x1A);
        handoff(aB, x0B, x1B);

        // ---- L2: 64 -> 64, both ----
#pragma unroll
        for (int t = 0; t < 4; ++t) {
            aA[t] = *reinterpret_cast<const f32x4*>(&sBias[64 + 16 * t + 4 * g]);
            aB[t] = aA[t];
            aA[t] = MFMA16(w2h[t][0], x0A, aA[t]);
            aB[t] = MFMA16(w2h[t][0], x0B, aB[t]);
            aA[t] = MFMA16(w2h[t][1], x1A, aA[t]);
            aB[t] = MFMA16(w2h[t][1], x1B, aB[t]);
        }
        handoff(aA, x0A, x1A);
        handoff(aB, x0B, x1B);

        // ---- L3: 64 -> 64, both ----
#pragma unroll
        for (int t = 0; t < 4; ++t) {
            aA[t] = *reinterpret_cast<const f32x4*>(&sBias[128 + 16 * t + 4 * g]);
            aB[t] = aA[t];
            aA[t] = MFMA16(w3h[t][0], x0A, aA[t]);
            aB[t] = MFMA16(w3h[t][0], x0B, aB[t]);
            aA[t] = MFMA16(w3h[t][1], x1A, aA[t]);
            aB[t] = MFMA16(w3h[t][1], x1B, aB[t]);
        }
        handoff(aA, x0A, x1A);
        handoff(aB, x0B, x1B);

        // ---- L4: 64 -> 3, relu, store, both ----
        {
            f32x4 oA = *reinterpret_cast<const f32x4*>(&sBias[192 + 4 * g]);
            f32x4 oB = oA;
            oA = MFMA16(w4h[0], x0A, oA);
            oB = MFMA16(w4h[0], x0B, oB);
            oA = MFMA16(w4h[1], x1A, oA);
            oB = MFMA16(w4h[1], x1B, oB);
            if (g == 0 && tA * 16 + p < npts) {
                float* op = out + (size_t)(tA * 16 + p) * 3;
                op[0] = fmaxf(oA[0], 0.0f);
                op[1] = fmaxf(oA[1], 0.0f);
                op[2] = fmaxf(oA[2], 0.0f);
            }
            if (g == 0 && hasB && tB * 16 + p < npts) {
                float* op = out + (size_t)(tB * 16 + p) * 3;
                op[0] = fmaxf(oB[0], 0.0f);
                op[1] = fmaxf(oB[1], 0.0f);
                op[2] = fmaxf(oB[2], 0.0f);
            }
        }

        xA = xnA; xB = xnB;
    }
}

extern "C" void kernel_launch(void* const* d_in, const int* in_sizes, int n_in,
                              void* d_out, int out_size, void* d_ws, size_t ws_size,
                              hipStream_t stream) {
    const float* X  = (const float*)d_in[0];
    const float* HT = (const float*)d_in[1];
    const float* W1 = (const float*)d_in[2];
    const float* B1 = (const float*)d_in[3];
    const float* W2 = (const float*)d_in[4];
    const float* B2 = (const float*)d_in[5];
    const float* W3 = (const float*)d_in[6];
    const float* B3 = (const float*)d_in[7];
    const float* W4 = (const float*)d_in[8];
    const float* B4 = (const float*)d_in[9];
    float* out = (float*)d_out;

    const int npts = in_sizes[0] / 2;
    // 512 blocks x 4 waves = 2048 waves, 2 tiles in flight each, 8 pair-iters
    // exactly (no tail). ~190 regs -> 2 waves/SIMD resident; 4 chains/SIMD.
    hipLaunchKernelGGL(hashnerf_mfma, dim3(512), dim3(256), 0, stream,
                       X, HT, W1, B1, W2, B2, W3, B3, W4, B4, out, npts);
}

// Round 12
// 125.441 us; speedup vs baseline: 1.0147x; 1.0147x over previous
//
#include <hip/hip_runtime.h>

// hashNeRF fused forward, MFMA edition, v8: zero-LDS permuted pipeline,
// full-residency grid (TLP round). [Resubmitted unchanged: round-11 bench
// failed with GPUAcquisitionTimeout — experiment still unmeasured.]
//
// Verified: hash == parity(ix)^parity(iy), only HT[0:2,0:4,0:2] read; fragment
// layouts A row=lane&15 k=8*(lane>>4)+e / B col=lane&15 / D col=lane&15
// row=4*(lane>>4)+reg; pure bf16 absmax 0.0 (r8); neuron-permutation
// pi(16t+4g+r)=32(t&1)+4(t>>1)+8g+r makes D-quads == next layer's B-frags
// with identity k (r9, absmax 0.0, 128 VGPR).
// r9/r10 lesson: in-wave 2-tile ILP is NULL (42.3 -> 45.0 us) and fewer waves
// made it worse; kernel is VALU-issue-heavy (~47K of 108K cyc issuing VALU)
// at only ~2-3 effective waves/SIMD -> ~50% dep-stall bubbles. The lever is
// RESIDENT WAVES, not in-wave chains.
// Round-11/12 change (single variable): grid 768 -> 1024 blocks. At 128 regs,
// 4 waves/SIMD fit -> all 4096 waves resident (16/CU), exactly 8 tiles/wave
// (no ragged tail; r9's 768 blocks gave 10.67 tiles/wave).

typedef float  f32x4  __attribute__((ext_vector_type(4)));
typedef __bf16 bf16x8 __attribute__((ext_vector_type(8)));

#define MFMA16(A, B, C) __builtin_amdgcn_mfma_f32_16x16x32_bf16((A), (B), (C), 0, 0, 0)

__global__ __launch_bounds__(256) void hashnerf_mfma(
    const float* __restrict__ X,
    const float* __restrict__ HT,
    const float* __restrict__ W1, const float* __restrict__ B1,
    const float* __restrict__ W2, const float* __restrict__ B2,
    const float* __restrict__ W3, const float* __restrict__ B3,
    const float* __restrict__ W4, const float* __restrict__ B4,
    float* __restrict__ out, int npts)
{
    __shared__ __align__(16) float sBias[208];

    const int tid = threadIdx.x;
    if (tid < 64) {
        // stage biases PERMUTED: phys slot rho holds B[pi(rho)]
        const int pm = 32 * ((tid >> 4) & 1) + 4 * (tid >> 5)
                     + 8 * ((tid >> 2) & 3) + (tid & 3);
        sBias[tid]       = B1[pm];
        sBias[64 + tid]  = B2[pm];
        sBias[128 + tid] = B3[pm];
    }
    if (tid < 16) sBias[192 + tid] = (tid < 3) ? B4[tid] : 0.0f;
    __syncthreads();

    const int l = tid & 63;
    const int p = l & 15;      // point-in-tile (B/D col), A row
    const int g = l >> 4;      // lane group: K-chunk / D-row-quad selector

    // permuted output column for A fragments of W1/W2/W3: pi(16t + p)
    int po[4];
#pragma unroll
    for (int t = 0; t < 4; ++t)
        po[t] = 32 * (t & 1) + 4 * (t >> 1) + 8 * (p >> 2) + (p & 3);

    // ---- one-time per-wave: bf16 weight fragments (A = W^T) ----
    bf16x8 w1h[4];                       // L1: 32->64, out-permuted
#pragma unroll
    for (int t = 0; t < 4; ++t)
#pragma unroll
        for (int e = 0; e < 8; ++e)
            w1h[t][e] = (__bf16)W1[(8 * g + e) * 64 + po[t]];

    bf16x8 w2h[4][2], w3h[4][2];         // L2/L3: 64->64, k identity, out-permuted
#pragma unroll
    for (int t = 0; t < 4; ++t)
#pragma unroll
        for (int s = 0; s < 2; ++s)
#pragma unroll
            for (int e = 0; e < 8; ++e) {
                w2h[t][s][e] = (__bf16)W2[(32 * s + 8 * g + e) * 64 + po[t]];
                w3h[t][s][e] = (__bf16)W3[(32 * s + 8 * g + e) * 64 + po[t]];
            }

    bf16x8 w4h[2];                       // L4: 64->3, k identity, out identity
#pragma unroll
    for (int s = 0; s < 2; ++s)
#pragma unroll
        for (int e = 0; e < 8; ++e)
            w4h[s][e] = (p < 3) ? (__bf16)W4[(32 * s + 8 * g + e) * 3 + p] : (__bf16)0.0f;

    // hash-table constants (the only 16 floats ever used)
    float t0[8], t1[8];
#pragma unroll
    for (int e = 0; e < 8; ++e) { t0[e] = HT[e]; t1[e] = HT[524288 + e]; }

    // this lane's 4 resolution levels (levels 4g..4g+3)
    const float NVA[4] = {16.f, 17.f, 19.f, 21.f};
    const float NVB[4] = {23.f, 25.f, 27.f, 30.f};
    const float NVC[4] = {33.f, 36.f, 40.f, 44.f};
    const float NVD[4] = {48.f, 53.f, 58.f, 64.f};
    float nv4[4];
#pragma unroll
    for (int j = 0; j < 4; ++j)
        nv4[j] = (g == 0) ? NVA[j] : (g == 1) ? NVB[j] : (g == 2) ? NVC[j] : NVD[j];

    // in-register handoff: lrelu + bf16, D quads -> next layer's B fragments
    auto handoff = [&](const f32x4 (&a)[4], bf16x8& x0, bf16x8& x1) {
#pragma unroll
        for (int r = 0; r < 4; ++r) {
            float v0 = fmaxf(a[0][r], 0.01f * a[0][r]);
            float v1 = fmaxf(a[1][r], 0.01f * a[1][r]);
            float v2 = fmaxf(a[2][r], 0.01f * a[2][r]);
            float v3 = fmaxf(a[3][r], 0.01f * a[3][r]);
            x0[r]     = (__bf16)v0;   // k = 8g+r
            x0[4 + r] = (__bf16)v2;   // k = 8g+4+r
            x1[r]     = (__bf16)v1;   // k = 32+8g+r
            x1[4 + r] = (__bf16)v3;   // k = 32+8g+4+r
        }
    };

    const int wave_global = blockIdx.x * 4 + (tid >> 6);
    const int nw = gridDim.x * 4;
    const int ntiles = (npts + 15) >> 4;
    const float2* X2 = reinterpret_cast<const float2*>(X);

    int tile = wave_global;
    float2 xv = make_float2(0.f, 0.f);
    if (tile < ntiles) xv = X2[min(tile * 16 + p, npts - 1)];

    for (; tile < ntiles; tile += nw) {
        const int nt = tile + nw;
        float2 xnext = xv;
        if (nt < ntiles) xnext = X2[min(nt * 16 + p, npts - 1)];

        // ---- encode: lane produces enc[8g..8g+7] of its point ----
        bf16x8 bh;
#pragma unroll
        for (int j2 = 0; j2 < 4; ++j2) {
            const float nv = nv4[j2];
            const float sx = xv.x * nv, sy = xv.y * nv;
            const float fx = sx - floorf(sx), fy = sy - floorf(sy);
            const unsigned ix = (unsigned)sx, iy = (unsigned)sy;
            const bool px = (ix & 1u) != 0u, py = (iy & 1u) != 0u;
            const bool pz = px != py;
            const float cx = 1.f - fx, cy = 1.f - fy;
            const float q0 = cx * cy, q1 = cx * fy, q2 = fx * cy, q3 = fx * fy;
            float a0 = q0 * t0[0];
            a0 = fmaf(q1, py ? t1[2] : t0[2], a0);
            a0 = fmaf(q2, px ? t1[4] : t0[4], a0);
            a0 = fmaf(q3, pz ? t1[6] : t0[6], a0);
            float a1 = q0 * t0[1];
            a1 = fmaf(q1, py ? t1[3] : t0[3], a1);
            a1 = fmaf(q2, px ? t1[5] : t0[5], a1);
            a1 = fmaf(q3, pz ? t1[7] : t0[7], a1);
            bh[2 * j2]     = (__bf16)a0;
            bh[2 * j2 + 1] = (__bf16)a1;
        }

        // ---- L1: 32 -> 64 (out-permuted) ----
        f32x4 acc[4];
#pragma unroll
        for (int t = 0; t < 4; ++t) {
            acc[t] = *reinterpret_cast<const f32x4*>(&sBias[16 * t + 4 * g]);
            acc[t] = MFMA16(w1h[t], bh, acc[t]);
        }
        bf16x8 x0, x1;
        handoff(acc, x0, x1);

        // ---- L2: 64 -> 64 ----
#pragma unroll
        for (int t = 0; t < 4; ++t) {
            acc[t] = *reinterpret_cast<const f32x4*>(&sBias[64 + 16 * t + 4 * g]);
            acc[t] = MFMA16(w2h[t][0], x0, acc[t]);
            acc[t] = MFMA16(w2h[t][1], x1, acc[t]);
        }
        handoff(acc, x0, x1);

        // ---- L3: 64 -> 64 ----
#pragma unroll
        for (int t = 0; t < 4; ++t) {
            acc[t] = *reinterpret_cast<const f32x4*>(&sBias[128 + 16 * t + 4 * g]);
            acc[t] = MFMA16(w3h[t][0], x0, acc[t]);
            acc[t] = MFMA16(w3h[t][1], x1, acc[t]);
        }
        handoff(acc, x0, x1);

        // ---- L4: 64 -> 3, relu, store ----
        {
            f32x4 ao = *reinterpret_cast<const f32x4*>(&sBias[192 + 4 * g]);
            ao = MFMA16(w4h[0], x0, ao);
            ao = MFMA16(w4h[1], x1, ao);
            if (g == 0 && tile * 16 + p < npts) {
                float* op = out + (size_t)(tile * 16 + p) * 3;
                op[0] = fmaxf(ao[0], 0.0f);
                op[1] = fmaxf(ao[1], 0.0f);
                op[2] = fmaxf(ao[2], 0.0f);
            }
        }

        xv = xnext;
    }
}

extern "C" void kernel_launch(void* const* d_in, const int* in_sizes, int n_in,
                              void* d_out, int out_size, void* d_ws, size_t ws_size,
                              hipStream_t stream) {
    const float* X  = (const float*)d_in[0];
    const float* HT = (const float*)d_in[1];
    const float* W1 = (const float*)d_in[2];
    const float* B1 = (const float*)d_in[3];
    const float* W2 = (const float*)d_in[4];
    const float* B2 = (const float*)d_in[5];
    const float* W3 = (const float*)d_in[6];
    const float* B3 = (const float*)d_in[7];
    const float* W4 = (const float*)d_in[8];
    const float* B4 = (const float*)d_in[9];
    float* out = (float*)d_out;

    const int npts = in_sizes[0] / 2;
    // 1024 blocks x 4 waves = 4096 waves: at 128 regs -> 4 waves/SIMD -> the
    // ENTIRE grid resident (16 waves/CU); exactly 8 tiles/wave, no ragged tail.
    hipLaunchKernelGGL(hashnerf_mfma, dim3(1024), dim3(256), 0, stream,
                       X, HT, W1, B1, W2, B2, W3, B3, W4, B4, out, npts);
}